// Round 1
// baseline (2516.562 us; speedup 1.0000x reference)
//
#include <hip/hip_runtime.h>

// Sqrtm via Newton-Schulz, B=256, D=256, iterN=5 (hardcoded: 3 loop iters + final).
//
// Algebra: with A = x/normA, I3 = 3I:
//   Z1 = 1.5 I - 0.5 A                  (elementwise)
//   repeat 3x:  W = A@Z ; T = 1.5 W - 0.5 (Z@W) ; Z = T@Z
//   final:      W = A@Z ; T = 1.5 W - 0.5 (W@Z) ; out = sqrt(normA) * (T@W)
// (uses Y_k = A @ Z_k, valid since all iterates are commuting polynomials in A)
//
// One workgroup (1024 threads) per batch element; full 256x256 C tile lives in
// registers (8x8 per thread), so in-place matmuls are safe: all global reads
// of A/B finish at the last staging barrier, before any C write.

#define D 256
#define NT 1024
#define BK 16
#define LDA_S 260   // As stride (padded, keeps b128 reads 16B-aligned)
#define LDB_S 288   // Bs stride; columns swizzled by +4*(c>>5) to use all 32 banks

__device__ __forceinline__ void mm256(const float* __restrict__ A,
                                      const float* __restrict__ B,
                                      float* __restrict__ C,
                                      const float* __restrict__ Aux,
                                      float alpha, float beta,
                                      float* As, float* Bs, int tid)
{
    const int tr = tid >> 5, tc = tid & 31;
    const int r0 = tr << 3, c0 = tc << 3;

    float acc[8][8];
#pragma unroll
    for (int i = 0; i < 8; ++i)
#pragma unroll
        for (int j = 0; j < 8; ++j) acc[i][j] = 0.f;

    // staging coords
    const int sr = tid >> 2;             // A: row 0..255
    const int sk = (tid & 3) << 2;       // A: k-col 0,4,8,12
    const int bk = tid >> 6;             // B: k-row 0..15
    const int bc = (tid & 63) << 2;      // B: col
    const int bo = bk * LDB_S + bc + ((bc >> 5) << 2);
    const int co = c0 + ((c0 >> 5) << 2);

    for (int kt = 0; kt < D; kt += BK) {
        __syncthreads();
        // stage A^T: As[k][r] = A[r][kt+k]
        const float4 av = *(const float4*)(A + sr * D + kt + sk);
        As[(sk + 0) * LDA_S + sr] = av.x;
        As[(sk + 1) * LDA_S + sr] = av.y;
        As[(sk + 2) * LDA_S + sr] = av.z;
        As[(sk + 3) * LDA_S + sr] = av.w;
        // stage B (swizzled): Bs[k][c'] = B[kt+k][c]
        const float4 bv = *(const float4*)(B + (kt + bk) * D + bc);
        *(float4*)(Bs + bo) = bv;
        __syncthreads();

#pragma unroll
        for (int k = 0; k < BK; ++k) {
            const float4 a0 = *(const float4*)(As + k * LDA_S + r0);
            const float4 a1 = *(const float4*)(As + k * LDA_S + r0 + 4);
            const float4 b0 = *(const float4*)(Bs + k * LDB_S + co);
            const float4 b1 = *(const float4*)(Bs + k * LDB_S + co + 4);
            const float a[8] = {a0.x, a0.y, a0.z, a0.w, a1.x, a1.y, a1.z, a1.w};
            const float b[8] = {b0.x, b0.y, b0.z, b0.w, b1.x, b1.y, b1.z, b1.w};
#pragma unroll
            for (int i = 0; i < 8; ++i)
#pragma unroll
                for (int j = 0; j < 8; ++j)
                    acc[i][j] = fmaf(a[i], b[j], acc[i][j]);
        }
    }

    // All global reads of A/B completed before the last post-staging barrier,
    // so writing C (which may alias A or B) is safe now.
#pragma unroll
    for (int i = 0; i < 8; ++i) {
        const int r = r0 + i;
        float4 o0, o1;
        o0.x = alpha * acc[i][0]; o0.y = alpha * acc[i][1];
        o0.z = alpha * acc[i][2]; o0.w = alpha * acc[i][3];
        o1.x = alpha * acc[i][4]; o1.y = alpha * acc[i][5];
        o1.z = alpha * acc[i][6]; o1.w = alpha * acc[i][7];
        if (Aux) {
            const float4 x0 = *(const float4*)(Aux + r * D + c0);
            const float4 x1 = *(const float4*)(Aux + r * D + c0 + 4);
            o0.x += beta * x0.x; o0.y += beta * x0.y;
            o0.z += beta * x0.z; o0.w += beta * x0.w;
            o1.x += beta * x1.x; o1.y += beta * x1.y;
            o1.z += beta * x1.z; o1.w += beta * x1.w;
        }
        *(float4*)(C + r * D + c0) = o0;
        *(float4*)(C + r * D + c0 + 4) = o1;
    }
}

__global__ __launch_bounds__(NT, 1) void sqrtm_ns_kernel(
    const float* __restrict__ x, float* __restrict__ out,
    float* __restrict__ Zbuf, float* __restrict__ Wbuf, int nbatch)
{
    __shared__ __align__(16) float As[BK * LDA_S];
    __shared__ __align__(16) float Bs[BK * LDB_S];
    __shared__ float red[NT / 64];
    __shared__ float scal[2];

    const int tid = threadIdx.x;
    float* Z = Zbuf + (size_t)blockIdx.x * D * D;  // indexed by BLOCK (ws fallback)
    float* W = Wbuf + (size_t)blockIdx.x * D * D;

    for (int b = blockIdx.x; b < nbatch; b += gridDim.x) {
        const float* X = x + (size_t)b * D * D;
        float* T = out + (size_t)b * D * D;

        // ---- normA = sum of all entries of x_b ----
        float s = 0.f;
        for (int i = 0; i < 16; ++i) {
            const float4 v = *(const float4*)(X + ((i * NT + tid) << 2));
            s += v.x + v.y + v.z + v.w;
        }
        for (int off = 32; off; off >>= 1) s += __shfl_down(s, off, 64);
        __syncthreads();  // protect red[] across outer-loop iterations
        if ((tid & 63) == 0) red[tid >> 6] = s;
        __syncthreads();
        if (tid == 0) {
            float t = 0.f;
            for (int i = 0; i < NT / 64; ++i) t += red[i];
            scal[0] = 1.0f / t;
            scal[1] = sqrtf(t);
        }
        __syncthreads();
        const float invN = scal[0], sqrtN = scal[1];

        // ---- Z1 = 1.5 I - 0.5 * invN * x ----
        for (int i = 0; i < 16; ++i) {
            const int e = (i * NT + tid) << 2;
            const int r = e >> 8, c = e & 255;
            const float4 v = *(const float4*)(X + e);
            float4 z;
            z.x = fmaf(-0.5f * invN, v.x, (r == c + 0) ? 1.5f : 0.f);
            z.y = fmaf(-0.5f * invN, v.y, (r == c + 1) ? 1.5f : 0.f);
            z.z = fmaf(-0.5f * invN, v.z, (r == c + 2) ? 1.5f : 0.f);
            z.w = fmaf(-0.5f * invN, v.w, (r == c + 3) ? 1.5f : 0.f);
            *(float4*)(Z + e) = z;
        }
        // (mm256 begins with __syncthreads: Z writes visible before staging)

        for (int it = 0; it < 3; ++it) {
            mm256(X, Z, W, nullptr, invN, 0.f, As, Bs, tid);  // W = A@Z  (= Y)
            mm256(Z, W, T, W, -0.5f, 1.5f, As, Bs, tid);      // T = 1.5W - 0.5 Z@W
            mm256(T, Z, Z, nullptr, 1.f, 0.f, As, Bs, tid);   // Z = T@Z (in-place safe)
        }
        mm256(X, Z, W, nullptr, invN, 0.f, As, Bs, tid);      // W = Y
        mm256(W, Z, T, W, -0.5f, 1.5f, As, Bs, tid);          // T = 0.5 Y(3I-Z)
        mm256(T, W, T, nullptr, sqrtN, 0.f, As, Bs, tid);     // out = sqrtN * T@W
        __syncthreads();
    }
}

extern "C" void kernel_launch(void* const* d_in, const int* in_sizes, int n_in,
                              void* d_out, int out_size, void* d_ws, size_t ws_size,
                              hipStream_t stream)
{
    const float* x = (const float*)d_in[0];
    float* out = (float*)d_out;
    const int nbatch = 256;  // B from reference; out_size = 256*256*256

    // ws layout: [grid][D*D] Z, then [grid][D*D] W. Prefer grid=256 (one WG/CU);
    // degrade gracefully if ws is smaller.
    const size_t matBytes = (size_t)D * D * sizeof(float);
    int grid = (int)(ws_size / (2 * matBytes));
    if (grid > nbatch) grid = nbatch;
    if (grid < 1) grid = 1;  // pathological ws; still correct (ws must hold >=2 matrices)

    float* Zbuf = (float*)d_ws;
    float* Wbuf = Zbuf + (size_t)grid * D * D;

    sqrtm_ns_kernel<<<dim3(grid), dim3(NT), 0, stream>>>(x, out, Zbuf, Wbuf, nbatch);
}

// Round 5
// 1305.191 us; speedup vs baseline: 1.9281x; 1.9281x over previous
//
#include <hip/hip_runtime.h>

// Sqrtm via Newton-Schulz, B=256, D=256, iterN=5.
// Round 5: round-4 multi-launch structure, but MFMA path switched from f16 to
// bf16 with ext_vector_type(8) short operands -- the guide's compile-verified
// gfx950 pattern (m89/m91). Rounds 2-4 all produced exact-stub output and all
// shared the _Float16 / f16-MFMA-builtin surface (suspected hard compile error
// -> .so never ran); this file contains no _Float16 and no __hip_bfloat16.
//
// fp32 emulated as 3-term bf16 split with round-to-nearest conversions:
//   a = ah + al + e,  |al| <= 2^-8|a|, |e| <= 2^-16|a| (RTN, sign-symmetric)
//   A@B ~= Ah@Bh + Al@Bh + Ah@Bl   (dropped al*bl ~ 2^-16, zero-mean)
//
// Chain (A = x/normA; invariant Y_k = A@Z_k, all iterates commute as polys
// in A; verified against the reference's ZY = 0.5*(3I - Z)@Y form):
//   Z1 = 1.5I - 0.5A
//   3x:  W = A@Z ; T = 1.5W - 0.5(Z@W) ; Z = T@Z
//   fin: W = A@Z ; T = 1.5W - 0.5(W@Z) ; out = sqrt(normA) * (T@W)

#define DD 256
#define MATN 65536  // DD*DD
#define LR 40       // short LDS row stride: 32 data + 8 pad (80 B, 16B-aligned)

typedef short s16x8 __attribute__((ext_vector_type(8)));
typedef float f32x4 __attribute__((ext_vector_type(4)));

#define AM_CONST 0
#define AM_INV 1
#define AM_SQRT 2

__device__ __forceinline__ short bf16rtn(float f) {
    unsigned u = __float_as_uint(f);
    u += 0x7FFFu + ((u >> 16) & 1u);   // round-to-nearest-even
    return (short)(u >> 16);
}
__device__ __forceinline__ float bf16tof(short h) {
    return __uint_as_float(((unsigned)(unsigned short)h) << 16);
}

// ---- setup: sc[2b]=1/normA, sc[2b+1]=sqrt(normA); Z1 = 1.5I - 0.5*invN*x ----
__global__ __launch_bounds__(256) void setup_kernel(const float* x, float* Z,
                                                    float* sc)
{
    const int lb = blockIdx.x, tid = threadIdx.x;
    const float* X = x + (size_t)lb * MATN;
    float* Zb = Z + (size_t)lb * MATN;
    __shared__ float red[4];
    __shared__ float sInv;

    float s = 0.f;
    for (int i = 0; i < 64; ++i) {
        const float4 v = *(const float4*)(X + ((i * 256 + tid) << 2));
        s += v.x + v.y + v.z + v.w;
    }
    for (int o = 32; o; o >>= 1) s += __shfl_down(s, o, 64);
    if ((tid & 63) == 0) red[tid >> 6] = s;
    __syncthreads();
    if (tid == 0) {
        const float t = red[0] + red[1] + red[2] + red[3];
        sc[2 * lb] = 1.f / t;
        sc[2 * lb + 1] = sqrtf(t);
        sInv = 1.f / t;
    }
    __syncthreads();
    const float invN = sInv;

    for (int i = 0; i < 64; ++i) {
        const int e = (i * 256 + tid) << 2;
        const int r = e >> 8, c = e & 255;
        const float4 v = *(const float4*)(X + e);
        float4 z;
        z.x = fmaf(-0.5f * invN, v.x, (r == c + 0) ? 1.5f : 0.f);
        z.y = fmaf(-0.5f * invN, v.y, (r == c + 1) ? 1.5f : 0.f);
        z.z = fmaf(-0.5f * invN, v.z, (r == c + 2) ? 1.5f : 0.f);
        z.w = fmaf(-0.5f * invN, v.w, (r == c + 3) ? 1.5f : 0.f);
        *(float4*)(Zb + e) = z;
    }
}

// ---- d2d copy kernel, n4 = float4 count ----
__global__ __launch_bounds__(256) void copy_kernel(const float* src, float* dst,
                                                   int n4)
{
    const int i = blockIdx.x * 256 + threadIdx.x;
    if (i < n4) ((float4*)dst)[i] = ((const float4*)src)[i];
}

// ---- batched GEMM: C = alpha*(A@B) [+ beta*Aux], fp32 I/O, split-bf16 MFMA.
// grid = 4*n blocks: bid>>2 = local batch, bid&3 = 128x128 C tile.
__global__ __launch_bounds__(256) void gemm_ns(
    const float* A, const float* B, float* C, const float* Aux,
    const float* sc, int amode, float aconst, float beta)
{
    __shared__ __align__(16) short Ah[128 * LR];
    __shared__ __align__(16) short Al[128 * LR];
    __shared__ __align__(16) short Bh[128 * LR];
    __shared__ __align__(16) short Bl[128 * LR];

    const int bid = blockIdx.x;
    const int lb = bid >> 2, t = bid & 3;
    const size_t off = (size_t)lb * MATN;
    const int tileR = (t >> 1) << 7, tileC = (t & 1) << 7;
    const int tid = threadIdx.x, lane = tid & 63, wave = tid >> 6;
    const int wr = wave >> 1, wc = wave & 1, ln = lane & 15, quad = lane >> 4;

    const float alpha = (amode == AM_INV)  ? sc[2 * lb]
                      : (amode == AM_SQRT) ? sc[2 * lb + 1] : aconst;

    f32x4 acc[4][4];
#pragma unroll
    for (int i = 0; i < 4; ++i)
#pragma unroll
        for (int j = 0; j < 4; ++j) {
            acc[i][j][0] = 0.f; acc[i][j][1] = 0.f;
            acc[i][j][2] = 0.f; acc[i][j][3] = 0.f;
        }

    const float* Ab = A + off;
    const float* Bb = B + off;

    for (int kt = 0; kt < DD; kt += 32) {
        __syncthreads();
#pragma unroll
        for (int i = 0; i < 4; ++i) {
            const int flat = i * 256 + tid;
            {   // A panel 128x32, row-major [m][k], coalesced float4
                const int row = flat >> 3, kc = (flat & 7) << 2;
                const float4 v = *(const float4*)(Ab + (size_t)(tileR + row) * DD + kt + kc);
                const short h0 = bf16rtn(v.x), h1 = bf16rtn(v.y),
                            h2 = bf16rtn(v.z), h3 = bf16rtn(v.w);
                short* ph = Ah + row * LR + kc;
                short* pl = Al + row * LR + kc;
                ph[0] = h0; pl[0] = bf16rtn(v.x - bf16tof(h0));
                ph[1] = h1; pl[1] = bf16rtn(v.y - bf16tof(h1));
                ph[2] = h2; pl[2] = bf16rtn(v.z - bf16tof(h2));
                ph[3] = h3; pl[3] = bf16rtn(v.w - bf16tof(h3));
            }
            {   // B panel 32x128, stored transposed [n][k]
                const int kr = flat >> 5, nc = (flat & 31) << 2;
                const float4 v = *(const float4*)(Bb + (size_t)(kt + kr) * DD + tileC + nc);
                const short h0 = bf16rtn(v.x), h1 = bf16rtn(v.y),
                            h2 = bf16rtn(v.z), h3 = bf16rtn(v.w);
                Bh[(nc + 0) * LR + kr] = h0; Bl[(nc + 0) * LR + kr] = bf16rtn(v.x - bf16tof(h0));
                Bh[(nc + 1) * LR + kr] = h1; Bl[(nc + 1) * LR + kr] = bf16rtn(v.y - bf16tof(h1));
                Bh[(nc + 2) * LR + kr] = h2; Bl[(nc + 2) * LR + kr] = bf16rtn(v.z - bf16tof(h2));
                Bh[(nc + 3) * LR + kr] = h3; Bl[(nc + 3) * LR + kr] = bf16rtn(v.w - bf16tof(h3));
            }
        }
        __syncthreads();

        // A-frags for this wave's 4 m-tiles (layout: A[m=ln][k=quad*8+j])
        s16x8 ahf[4], alf[4];
#pragma unroll
        for (int i = 0; i < 4; ++i) {
            const int ro = (wr * 64 + i * 16 + ln) * LR + quad * 8;
            ahf[i] = *(const s16x8*)(Ah + ro);
            alf[i] = *(const s16x8*)(Al + ro);
        }
#pragma unroll
        for (int j = 0; j < 4; ++j) {
            const int co = (wc * 64 + j * 16 + ln) * LR + quad * 8;
            const s16x8 bh = *(const s16x8*)(Bh + co);
            const s16x8 bl = *(const s16x8*)(Bl + co);
#pragma unroll
            for (int i = 0; i < 4; ++i) {
                acc[i][j] = __builtin_amdgcn_mfma_f32_16x16x32_bf16(ahf[i], bh, acc[i][j], 0, 0, 0);
                acc[i][j] = __builtin_amdgcn_mfma_f32_16x16x32_bf16(alf[i], bh, acc[i][j], 0, 0, 0);
                acc[i][j] = __builtin_amdgcn_mfma_f32_16x16x32_bf16(ahf[i], bl, acc[i][j], 0, 0, 0);
            }
        }
    }

    // Epilogue. C/D layout: col=lane&15, row=quad*4+reg (m89/m91-verified).
    float* Cb = C + off;
    const float* Xb = Aux ? Aux + off : nullptr;
#pragma unroll
    for (int i = 0; i < 4; ++i)
#pragma unroll
        for (int j = 0; j < 4; ++j) {
            const int col = tileC + wc * 64 + j * 16 + ln;
#pragma unroll
            for (int r = 0; r < 4; ++r) {
                const int row = tileR + wr * 64 + i * 16 + quad * 4 + r;
                const int idx = row * DD + col;
                float v = alpha * acc[i][j][r];
                if (Xb) v = fmaf(beta, Xb[idx], v);
                Cb[idx] = v;
            }
        }
}

extern "C" void kernel_launch(void* const* d_in, const int* in_sizes, int n_in,
                              void* d_out, int out_size, void* d_ws, size_t ws_size,
                              hipStream_t stream)
{
    const float* x = (const float*)d_in[0];
    float* out = (float*)d_out;
    const int NB = 256;

    // ws layout: [512 floats scalars][P0: nbuf mats][P1: nbuf mats]
    const size_t wsf = ws_size / sizeof(float);
    int nbuf = 1;
    if (wsf > 512 + 2 * (size_t)MATN)
        nbuf = (int)((wsf - 512) / (2 * (size_t)MATN));
    if (nbuf > NB) nbuf = NB;
    if (nbuf < 1) nbuf = 1;

    float* sc = (float*)d_ws;
    float* P0 = sc + 512;
    float* P1 = P0 + (size_t)nbuf * MATN;

    for (int c0 = 0; c0 < NB; c0 += nbuf) {
        const int n = (NB - c0 < nbuf) ? (NB - c0) : nbuf;
        const float* xs = x + (size_t)c0 * MATN;
        float* os = out + (size_t)c0 * MATN;
        const dim3 G(4 * n), T(256);

#define GEMM(A, B, C, AUX, AM, AC, BT) \
    gemm_ns<<<G, T, 0, stream>>>((A), (B), (C), (AUX), sc, (AM), (AC), (BT))

        setup_kernel<<<n, 256, 0, stream>>>(xs, P0, sc);   // Z1->P0, scalars

        // it1 (Z in P0)
        GEMM(xs, P0, P1, nullptr, AM_INV, 0.f, 0.f);       // W = invN*(X@Z) -> P1
        GEMM(P0, P1, os, P1, AM_CONST, -0.5f, 1.5f);       // T = 1.5W-0.5(Z@W) -> os
        GEMM(os, P0, P1, nullptr, AM_CONST, 1.f, 0.f);     // Z = T@Z -> P1 (W dead)
        // it2 (Z in P1)
        GEMM(xs, P1, P0, nullptr, AM_INV, 0.f, 0.f);       // W -> P0
        GEMM(P1, P0, os, P0, AM_CONST, -0.5f, 1.5f);       // T -> os
        GEMM(os, P1, P0, nullptr, AM_CONST, 1.f, 0.f);     // Z -> P0
        // it3 (Z in P0)
        GEMM(xs, P0, P1, nullptr, AM_INV, 0.f, 0.f);       // W -> P1
        GEMM(P0, P1, os, P1, AM_CONST, -0.5f, 1.5f);       // T -> os
        GEMM(os, P0, P1, nullptr, AM_CONST, 1.f, 0.f);     // Z -> P1
        // final (Z in P1)
        GEMM(xs, P1, P0, nullptr, AM_INV, 0.f, 0.f);       // W = Y -> P0
        GEMM(P0, P1, os, P0, AM_CONST, -0.5f, 1.5f);       // T = 1.5W-0.5(W@Z) -> os
        copy_kernel<<<dim3(n * 64), T, 0, stream>>>(os, P1, n * (MATN / 4));  // T -> P1
        GEMM(P1, P0, os, nullptr, AM_SQRT, 0.f, 0.f);      // out = sqrtN*(T@W)
#undef GEMM
    }
}